// Round 6
// baseline (5049.593 us; speedup 1.0000x reference)
//
#include <hip/hip_runtime.h>
#include <math.h>

#define NIT 200
#define NN 128
#define TI 4
#define TJ 4
#define GI 32   // NN/TI
#define GJ 32   // NN/TJ
#define NTHREADS 1024
#define NWAVES 16

__global__ __attribute__((amdgpu_flat_work_group_size(NTHREADS, NTHREADS),
                          amdgpu_waves_per_eu(4, 4)))
void tv_kernel(const float* __restrict__ Min, const float* __restrict__ tvr,
               float* __restrict__ out, int Nb)
{
  const float MUc = 0.25f;
  const int b   = blockIdx.x;
  const int tid = threadIdx.x;
  const int tx  = tid & (GJ - 1);   // 0..31
  const int ty  = tid >> 5;         // 0..31
  const int lane = tid & 63;
  const int wv   = tid >> 6;        // 0..15
  const int i0 = ty * TI;
  const int j0 = tx * TJ;

  // m lives in LDS (read 2x/iter); frees 32 regs/thread of state.
  // layout: [elem][tid] -> bank = tid%32, conflict-free.
  __shared__ float m_lds[TI * TJ * NTHREADS];        // 64 KB
  // halo buffers [buf][comp-row][ty][tx] -> bank = tx, conflict-free.
  __shared__ float sTop [2][TJ][GI][GJ];             // 16 KB
  __shared__ float sLeft[2][TI][GI][GJ];             // 16 KB
  __shared__ float4 sRed[2][NWAVES];                 // parity-buffered
  // total ~128.5 KB -> 1 block/CU, 4 waves/SIMD, 128-reg budget (state fits).

  const float r = tvr[0];

  // register state: 5 arrays x 16 = 80 floats (+temps) -> fits 128 VGPRs
  float ux[TI][TJ], uy[TI][TJ], xx[TI][TJ], xy[TI][TJ], t[TI][TJ];

  const float* Mb = Min + (size_t)b * NN * NN;
#pragma unroll
  for (int di = 0; di < TI; ++di) {
    float4 v4 = *reinterpret_cast<const float4*>(Mb + (i0 + di) * NN + j0);
    m_lds[(di * TJ + 0) * NTHREADS + tid] = v4.x;
    m_lds[(di * TJ + 1) * NTHREADS + tid] = v4.y;
    m_lds[(di * TJ + 2) * NTHREADS + tid] = v4.z;
    m_lds[(di * TJ + 3) * NTHREADS + tid] = v4.w;
#pragma unroll
    for (int dj = 0; dj < TJ; ++dj) {
      ux[di][dj] = 0.f; uy[di][dj] = 0.f;
      xx[di][dj] = 0.f; xy[di][dj] = 0.f;
      t[di][dj] = 0.f;
    }
  }
  __syncthreads();

  int par = 0;
  // block reduce of 4 floats across 16 waves; result in all lanes.
  auto blk_red4 = [&](float v0, float v1, float v2, float v3) {
#pragma unroll
    for (int off = 32; off >= 1; off >>= 1) {
      v0 += __shfl_xor(v0, off, 64);
      v1 += __shfl_xor(v1, off, 64);
      v2 += __shfl_xor(v2, off, 64);
      v3 += __shfl_xor(v3, off, 64);
    }
    if (lane == 0) sRed[par][wv] = make_float4(v0, v1, v2, v3);
    __syncthreads();
    float4 q = sRed[par][lane & (NWAVES - 1)];
#pragma unroll
    for (int off = 1; off < NWAVES; off <<= 1) {
      q.x += __shfl_xor(q.x, off, 64); q.y += __shfl_xor(q.y, off, 64);
      q.z += __shfl_xor(q.z, off, 64); q.w += __shfl_xor(q.w, off, 64);
    }
    par ^= 1;
    return q;
  };
  auto blk_red2 = [&](float v0, float v1) {
    float4 q = blk_red4(v0, v1, 0.f, 0.f);
    return make_float2(q.x, q.y);
  };

  // Newton for the two per-component Duchi thresholds. S0/S1 = L1 sums.
  // Terminates on fixed point (tn==t) or segment stability (equal counts).
  auto newton_rounds = [&](auto getabs, float S0, float S1, float rad,
                           float& wsx, float& wsy, float& oxv, float& oyv) {
    const float invD = 1.f / 16384.f;
    float t0, t1; bool d0 = false, d1 = false;
    if (S0 <= rad) { t0 = 0.f; d0 = true; }
    else { t0 = fmaxf((S0 - rad) * invD, wsx); }
    if (S1 <= rad) { t1 = 0.f; d1 = true; }
    else { t1 = fmaxf((S1 - rad) * invD, wsy); }
    float np0 = -1.f, np1 = -1.f;
    for (int k = 0; k < 40 && !(d0 && d1); ++k) {
      float sa0 = 0.f, c0 = 0.f, sa1 = 0.f, c1 = 0.f;
#pragma unroll
      for (int di = 0; di < TI; ++di)
#pragma unroll
        for (int dj = 0; dj < TJ; ++dj) {
          float a0v, a1v; getabs(di, dj, a0v, a1v);
          if (a0v > t0) { sa0 += a0v; c0 += 1.f; }
          if (a1v > t1) { sa1 += a1v; c1 += 1.f; }
        }
      float4 rd = blk_red4(sa0, c0, sa1, c1);
      if (!d0) {
        if (rd.y < 0.5f) { t0 = (S0 - rad) * invD; np0 = -1.f; }
        else {
          float tn = __fdividef(rd.x - rad, rd.y);
          if (rd.y == np0 || tn == t0) d0 = true;
          t0 = tn; np0 = rd.y;
        }
      }
      if (!d1) {
        if (rd.w < 0.5f) { t1 = (S1 - rad) * invD; np1 = -1.f; }
        else {
          float tn = __fdividef(rd.z - rad, rd.w);
          if (rd.w == np1 || tn == t1) d1 = true;
          t1 = tn; np1 = rd.w;
        }
      }
    }
    oxv = t0; oyv = t1; wsx = t0; wsy = t1;
  };

  // div pass: t = m - div(ux,uy); reads buf0 halos, writes t-halos to buf1.
  auto div_pass = [&]() {
#pragma unroll
    for (int di = 0; di < TI; ++di) {
      const int i = i0 + di;
#pragma unroll
      for (int dj = 0; dj < TJ; ++dj) {
        const int j = j0 + dj;
        float up, lf;
        if (di > 0) up = ux[di - 1][dj];
        else { float h = sTop[0][dj][(ty > 0) ? ty - 1 : 0][tx]; up = (ty > 0) ? h : 0.f; }
        if (dj > 0) lf = uy[di][dj - 1];
        else { float h = sLeft[0][di][ty][(tx > 0) ? tx - 1 : 0]; lf = (tx > 0) ? h : 0.f; }
        float vxv = (i == NN - 1) ? 0.f : ux[di][dj];
        float vyv = (j == NN - 1) ? 0.f : uy[di][dj];
        float tt = m_lds[(di * TJ + dj) * NTHREADS + tid] - ((vxv - up) + (vyv - lf));
        t[di][dj] = tt;
        if (di == 0) sTop[1][dj][ty][tx] = tt;
        if (dj == 0) sLeft[1][di][ty][tx] = tt;
      }
    }
  };

  // grad pass: reads buf1 halos; consume(di,dj,gx,gy) with (gx,gy)=grad(t).
  auto grad_pass = [&](auto&& consume) {
#pragma unroll
    for (int di = 0; di < TI; ++di) {
      const int i = i0 + di;
#pragma unroll
      for (int dj = 0; dj < TJ; ++dj) {
        const int j = j0 + dj;
        float dn, rt;
        if (di < TI - 1) dn = t[di + 1][dj];
        else dn = sTop[1][dj][(ty < GI - 1) ? ty + 1 : ty][tx];
        if (dj < TJ - 1) rt = t[di][dj + 1];
        else rt = sLeft[1][di][ty][(tx < GJ - 1) ? tx + 1 : tx];
        float gx = (i == NN - 1) ? 0.f : dn - t[di][dj];
        float gy = (j == NN - 1) ? 0.f : rt - t[di][dj];
        consume(di, dj, gx, gy);
      }
    }
  };

  float A = 0.f;
  float w1x = -1.f, w1y = -1.f, w3x = -1.f, w3y = -1.f;  // warm starts
  float S0p = 0.f, S1p = 0.f;   // fused P1 sums (|u - xi|) from prev P4b
  float thx, thy;
  const float rad3 = r * (MUc * 0.5f);

#pragma unroll 1
  for (int it = 0; it < NIT; ++it) {
    const float a_ = 0.5f * (MUc + sqrtf(MUc * (MUc + 4.f * A)));

    // ---- P1 thresholds (A==0 at it==0 -> radius 0 -> identity)
    if (it == 0) { thx = INFINITY; thy = INFINITY; }
    else newton_rounds([&](int di, int dj, float& a0v, float& a1v) {
                         a0v = fabsf(ux[di][dj] - xx[di][dj]);
                         a1v = fabsf(uy[di][dj] - xy[di][dj]);
                       }, S0p, S1p, r * A, w1x, w1y, thx, thy);

    // ---- P2a: y = cu*u + cv*clamp(u-xi, ±th); write y halos (buf0)
    {
      const float inv = 1.f / (A + a_);
      const float cu = A * inv, cv = a_ * inv;
#pragma unroll
      for (int di = 0; di < TI; ++di)
#pragma unroll
        for (int dj = 0; dj < TJ; ++dj) {
          float vx = fminf(fmaxf(ux[di][dj] - xx[di][dj], -thx), thx);
          float vy = fminf(fmaxf(uy[di][dj] - xy[di][dj], -thy), thy);
          ux[di][dj] = ux[di][dj] * cu + vx * cv;
          uy[di][dj] = uy[di][dj] * cu + vy * cv;
        }
#pragma unroll
      for (int dj = 0; dj < TJ; ++dj) sTop[0][dj][ty][tx] = ux[TI - 1][dj];
#pragma unroll
      for (int di = 0; di < TI; ++di) sLeft[0][di][ty][tx] = uy[di][TJ - 1];
    }
    __syncthreads();
    div_pass();            // t = M - div(y)
    __syncthreads();

    // ---- P2b: u_pre = y - (mu/2) grad(t); fused P3 L1-sums
    {
      float s0 = 0.f, s1 = 0.f;
      grad_pass([&](int di, int dj, float gx, float gy) {
        float nux = ux[di][dj] - 0.125f * gx;
        float nuy = uy[di][dj] - 0.125f * gy;
        ux[di][dj] = nux; uy[di][dj] = nuy;
        s0 += fabsf(nux);
        s1 += fabsf(nuy);
      });
      float2 S3 = blk_red2(s0, s1);

      // ---- P3: u = clamp(u_pre, ±th3)
      newton_rounds([&](int di, int dj, float& a0v, float& a1v) {
                      a0v = fabsf(ux[di][dj]); a1v = fabsf(uy[di][dj]);
                    }, S3.x, S3.y, rad3, w3x, w3y, thx, thy);
    }
    // ---- P4a: apply clamp; write u halos (buf0)
#pragma unroll
    for (int di = 0; di < TI; ++di)
#pragma unroll
      for (int dj = 0; dj < TJ; ++dj) {
        ux[di][dj] = fminf(fmaxf(ux[di][dj], -thx), thx);
        uy[di][dj] = fminf(fmaxf(uy[di][dj], -thy), thy);
      }
#pragma unroll
    for (int dj = 0; dj < TJ; ++dj) sTop[0][dj][ty][tx] = ux[TI - 1][dj];
#pragma unroll
    for (int di = 0; di < TI; ++di) sLeft[0][di][ty][tx] = uy[di][TJ - 1];
    __syncthreads();
    div_pass();            // t = Mnew
    __syncthreads();

    // ---- P4b: xi += a*grad(Mnew); fused next-P1 L1-sums
    {
      float s0 = 0.f, s1 = 0.f;
      grad_pass([&](int di, int dj, float gx, float gy) {
        xx[di][dj] += a_ * gx;
        xy[di][dj] += a_ * gy;
        s0 += fabsf(ux[di][dj] - xx[di][dj]);
        s1 += fabsf(uy[di][dj] - xy[di][dj]);
      });
      float2 SP = blk_red2(s0, s1);
      S0p = SP.x; S1p = SP.y;
    }
    A += a_;
  }

  // outputs: M1 = last Mnew (in t), u interleaved (last-dim 2)
  float* outM = out + (size_t)b * NN * NN;
  float* outU = out + (size_t)Nb * NN * NN + (size_t)b * NN * NN * 2;
#pragma unroll
  for (int di = 0; di < TI; ++di)
#pragma unroll
    for (int dj = 0; dj < TJ; ++dj) {
      const int idx = (i0 + di) * NN + (j0 + dj);
      outM[idx] = t[di][dj];
      reinterpret_cast<float2*>(outU)[idx] = make_float2(ux[di][dj], uy[di][dj]);
    }
}

extern "C" void kernel_launch(void* const* d_in, const int* in_sizes, int n_in,
                              void* d_out, int out_size, void* d_ws, size_t ws_size,
                              hipStream_t stream) {
  const float* M  = (const float*)d_in[0];
  const float* tv = (const float*)d_in[1];
  const int Nb = in_sizes[0] / (NN * NN);   // 8
  tv_kernel<<<dim3(Nb), dim3(NTHREADS), 0, stream>>>(M, tv, (float*)d_out, Nb);
}

// Round 7
// 3891.324 us; speedup vs baseline: 1.2977x; 1.2977x over previous
//
#include <hip/hip_runtime.h>
#include <math.h>

#define NIT 200
#define NN 128
#define TI 4
#define TJ 8
#define GI 32   // NN/TI
#define GJ 16   // NN/TJ
#define NTHREADS 512
#define NWAVES 8

__global__ __launch_bounds__(NTHREADS)
void tv_kernel(const float* __restrict__ Min, const float* __restrict__ tvr,
               float* __restrict__ out, int Nb)
{
  const float MUc = 0.25f;
  const int b   = blockIdx.x;
  const int tid = threadIdx.x;
  const int tx  = tid & (GJ - 1);   // 0..15
  const int ty  = tid >> 4;         // 0..31
  const int lane = tid & 63;
  const int wv   = tid >> 6;
  const int i0 = ty * TI;
  const int j0 = tx * TJ;

  // Full fields in LDS, tile layout [elem][tid]: bank = tid%32 (2 lanes/bank,
  // free). Neighbor threads are tid+16 (down) / tid+1 (right) -> same uniform
  // stride, still conflict-free. Frees 64 floats/thread of register state.
  __shared__ float m_lds[TI * TJ * NTHREADS];   // 64 KB, constant M field
  __shared__ float t_lds[TI * TJ * NTHREADS];   // 64 KB, scratch field t
  // u/y halo buffers for div (register-resident u): [comp-row][ty][tx]
  __shared__ float sTop [TJ][GI][GJ];           // 16 KB  (bottom rows)
  __shared__ float sLeft[TI][GI][GJ];           //  8 KB  (right cols)
  __shared__ float4 sRed[2][NWAVES];            // parity-buffered reduce
  // total ~152.3 KB -> 1 block/CU (grid is 8 blocks; costs nothing)

  const float r = tvr[0];

  // persistent register state: 4 arrays x 32 = 128 floats -> fits 128-reg cap
  float ux[TI][TJ], uy[TI][TJ], xx[TI][TJ], xy[TI][TJ];

  const float* Mb = Min + (size_t)b * NN * NN;
#pragma unroll
  for (int di = 0; di < TI; ++di) {
    float4 v0 = *reinterpret_cast<const float4*>(Mb + (i0 + di) * NN + j0);
    float4 v1 = *reinterpret_cast<const float4*>(Mb + (i0 + di) * NN + j0 + 4);
    m_lds[(di * TJ + 0) * NTHREADS + tid] = v0.x;
    m_lds[(di * TJ + 1) * NTHREADS + tid] = v0.y;
    m_lds[(di * TJ + 2) * NTHREADS + tid] = v0.z;
    m_lds[(di * TJ + 3) * NTHREADS + tid] = v0.w;
    m_lds[(di * TJ + 4) * NTHREADS + tid] = v1.x;
    m_lds[(di * TJ + 5) * NTHREADS + tid] = v1.y;
    m_lds[(di * TJ + 6) * NTHREADS + tid] = v1.z;
    m_lds[(di * TJ + 7) * NTHREADS + tid] = v1.w;
#pragma unroll
    for (int dj = 0; dj < TJ; ++dj) {
      ux[di][dj] = 0.f; uy[di][dj] = 0.f;
      xx[di][dj] = 0.f; xy[di][dj] = 0.f;
    }
  }
  __syncthreads();

  int par = 0;
  auto blk_red4 = [&](float v0, float v1, float v2, float v3) {
#pragma unroll
    for (int off = 32; off >= 1; off >>= 1) {
      v0 += __shfl_xor(v0, off, 64);
      v1 += __shfl_xor(v1, off, 64);
      v2 += __shfl_xor(v2, off, 64);
      v3 += __shfl_xor(v3, off, 64);
    }
    if (lane == 0) sRed[par][wv] = make_float4(v0, v1, v2, v3);
    __syncthreads();
    float4 acc = make_float4(0.f, 0.f, 0.f, 0.f);
#pragma unroll
    for (int w = 0; w < NWAVES; ++w) {
      float4 q = sRed[par][w];
      acc.x += q.x; acc.y += q.y; acc.z += q.z; acc.w += q.w;
    }
    par ^= 1;
    return acc;
  };
  auto blk_red2 = [&](float v0, float v1) {
#pragma unroll
    for (int off = 32; off >= 1; off >>= 1) {
      v0 += __shfl_xor(v0, off, 64);
      v1 += __shfl_xor(v1, off, 64);
    }
    if (lane == 0) sRed[par][wv] = make_float4(v0, v1, 0.f, 0.f);
    __syncthreads();
    float a0 = 0.f, a1 = 0.f;
#pragma unroll
    for (int w = 0; w < NWAVES; ++w) {
      float4 q = sRed[par][w];
      a0 += q.x; a1 += q.y;
    }
    par ^= 1;
    return make_float2(a0, a1);
  };

  // Newton for the two per-component Duchi thresholds. S0/S1 = L1 sums.
  // Terminates on fixed point (tn==t) or segment stability (equal counts).
  auto newton_rounds = [&](auto getabs, float S0, float S1, float rad,
                           float& wsx, float& wsy, float& oxv, float& oyv) {
    const float invD = 1.f / 16384.f;
    float t0, t1; bool d0 = false, d1 = false;
    if (S0 <= rad) { t0 = 0.f; d0 = true; }
    else { t0 = fmaxf((S0 - rad) * invD, wsx); }
    if (S1 <= rad) { t1 = 0.f; d1 = true; }
    else { t1 = fmaxf((S1 - rad) * invD, wsy); }
    float np0 = -1.f, np1 = -1.f;
    for (int k = 0; k < 40 && !(d0 && d1); ++k) {
      float sa0 = 0.f, c0 = 0.f, sa1 = 0.f, c1 = 0.f;
#pragma unroll
      for (int di = 0; di < TI; ++di)
#pragma unroll
        for (int dj = 0; dj < TJ; ++dj) {
          float a0v, a1v; getabs(di, dj, a0v, a1v);
          if (a0v > t0) { sa0 += a0v; c0 += 1.f; }
          if (a1v > t1) { sa1 += a1v; c1 += 1.f; }
        }
      float4 rd = blk_red4(sa0, c0, sa1, c1);
      if (!d0) {
        if (rd.y < 0.5f) { t0 = (S0 - rad) * invD; np0 = -1.f; }
        else {
          float tn = __fdividef(rd.x - rad, rd.y);
          if (rd.y == np0 || tn == t0) d0 = true;
          t0 = tn; np0 = rd.y;
        }
      }
      if (!d1) {
        if (rd.w < 0.5f) { t1 = (S1 - rad) * invD; np1 = -1.f; }
        else {
          float tn = __fdividef(rd.z - rad, rd.w);
          if (rd.w == np1 || tn == t1) d1 = true;
          t1 = tn; np1 = rd.w;
        }
      }
    }
    oxv = t0; oyv = t1; wsx = t0; wsy = t1;
  };

  // div pass: t_lds = m - div(ux,uy); reads u halos (sTop/sLeft), writes t_lds.
  auto div_pass = [&]() {
#pragma unroll
    for (int di = 0; di < TI; ++di) {
      const int i = i0 + di;
#pragma unroll
      for (int dj = 0; dj < TJ; ++dj) {
        const int j = j0 + dj;
        float up, lf;
        if (di > 0) up = ux[di - 1][dj];
        else { float h = sTop[dj][(ty > 0) ? ty - 1 : 0][tx]; up = (ty > 0) ? h : 0.f; }
        if (dj > 0) lf = uy[di][dj - 1];
        else { float h = sLeft[di][ty][(tx > 0) ? tx - 1 : 0]; lf = (tx > 0) ? h : 0.f; }
        float vxv = (i == NN - 1) ? 0.f : ux[di][dj];
        float vyv = (j == NN - 1) ? 0.f : uy[di][dj];
        float tt = m_lds[(di * TJ + dj) * NTHREADS + tid] - ((vxv - up) + (vyv - lf));
        t_lds[(di * TJ + dj) * NTHREADS + tid] = tt;
      }
    }
  };

  // grad pass: reads t_lds (own tile + tid+16 row + tid+1 col);
  // consume(di,dj,gx,gy) with (gx,gy)=grad(t).
  auto grad_pass = [&](auto&& consume) {
#pragma unroll
    for (int di = 0; di < TI; ++di) {
      const int i = i0 + di;
#pragma unroll
      for (int dj = 0; dj < TJ; ++dj) {
        const int j = j0 + dj;
        float tc = t_lds[(di * TJ + dj) * NTHREADS + tid];
        float gx, gy;
        if (i == NN - 1) gx = 0.f;
        else {
          float dn = (di < TI - 1) ? t_lds[((di + 1) * TJ + dj) * NTHREADS + tid]
                                   : t_lds[(0 * TJ + dj) * NTHREADS + tid + GJ];
          gx = dn - tc;
        }
        if (j == NN - 1) gy = 0.f;
        else {
          float rt = (dj < TJ - 1) ? t_lds[(di * TJ + dj + 1) * NTHREADS + tid]
                                   : t_lds[(di * TJ + 0) * NTHREADS + tid + 1];
          gy = rt - tc;
        }
        consume(di, dj, gx, gy);
      }
    }
  };

  float A = 0.f;
  float w1x = -1.f, w1y = -1.f, w3x = -1.f, w3y = -1.f;  // warm starts
  float S0p = 0.f, S1p = 0.f;   // fused P1 sums (|u - xi|) from prev P4b
  float thx, thy;
  const float rad3 = r * (MUc * 0.5f);

#pragma unroll 1
  for (int it = 0; it < NIT; ++it) {
    const float a_ = 0.5f * (MUc + sqrtf(MUc * (MUc + 4.f * A)));

    // ---- P1 thresholds (A==0 at it==0 -> radius 0 -> identity)
    if (it == 0) { thx = INFINITY; thy = INFINITY; }
    else newton_rounds([&](int di, int dj, float& a0v, float& a1v) {
                         a0v = fabsf(ux[di][dj] - xx[di][dj]);
                         a1v = fabsf(uy[di][dj] - xy[di][dj]);
                       }, S0p, S1p, r * A, w1x, w1y, thx, thy);

    // ---- P2a: y = cu*u + cv*clamp(u-xi, ±th); write y halos
    {
      const float inv = 1.f / (A + a_);
      const float cu = A * inv, cv = a_ * inv;
#pragma unroll
      for (int di = 0; di < TI; ++di)
#pragma unroll
        for (int dj = 0; dj < TJ; ++dj) {
          float vx = fminf(fmaxf(ux[di][dj] - xx[di][dj], -thx), thx);
          float vy = fminf(fmaxf(uy[di][dj] - xy[di][dj], -thy), thy);
          ux[di][dj] = ux[di][dj] * cu + vx * cv;
          uy[di][dj] = uy[di][dj] * cu + vy * cv;
        }
#pragma unroll
      for (int dj = 0; dj < TJ; ++dj) sTop[dj][ty][tx] = ux[TI - 1][dj];
#pragma unroll
      for (int di = 0; di < TI; ++di) sLeft[di][ty][tx] = uy[di][TJ - 1];
    }
    __syncthreads();
    div_pass();            // t = M - div(y)
    __syncthreads();

    // ---- P2b: u_pre = y - (mu/2) grad(t); fused P3 L1-sums
    {
      float s0 = 0.f, s1 = 0.f;
      grad_pass([&](int di, int dj, float gx, float gy) {
        float nux = ux[di][dj] - 0.125f * gx;
        float nuy = uy[di][dj] - 0.125f * gy;
        ux[di][dj] = nux; uy[di][dj] = nuy;
        s0 += fabsf(nux);
        s1 += fabsf(nuy);
      });
      float2 S3 = blk_red2(s0, s1);

      // ---- P3: u = clamp(u_pre, ±th3)
      newton_rounds([&](int di, int dj, float& a0v, float& a1v) {
                      a0v = fabsf(ux[di][dj]); a1v = fabsf(uy[di][dj]);
                    }, S3.x, S3.y, rad3, w3x, w3y, thx, thy);
    }
    // ---- P4a: apply clamp; write u halos
#pragma unroll
    for (int di = 0; di < TI; ++di)
#pragma unroll
      for (int dj = 0; dj < TJ; ++dj) {
        ux[di][dj] = fminf(fmaxf(ux[di][dj], -thx), thx);
        uy[di][dj] = fminf(fmaxf(uy[di][dj], -thy), thy);
      }
#pragma unroll
    for (int dj = 0; dj < TJ; ++dj) sTop[dj][ty][tx] = ux[TI - 1][dj];
#pragma unroll
    for (int di = 0; di < TI; ++di) sLeft[di][ty][tx] = uy[di][TJ - 1];
    __syncthreads();
    div_pass();            // t = Mnew
    __syncthreads();

    // ---- P4b: xi += a*grad(Mnew); fused next-P1 L1-sums
    {
      float s0 = 0.f, s1 = 0.f;
      grad_pass([&](int di, int dj, float gx, float gy) {
        xx[di][dj] += a_ * gx;
        xy[di][dj] += a_ * gy;
        s0 += fabsf(ux[di][dj] - xx[di][dj]);
        s1 += fabsf(uy[di][dj] - xy[di][dj]);
      });
      float2 SP = blk_red2(s0, s1);
      S0p = SP.x; S1p = SP.y;
    }
    A += a_;
  }

  // outputs: M1 = last Mnew (in t_lds), u interleaved (last-dim 2)
  float* outM = out + (size_t)b * NN * NN;
  float* outU = out + (size_t)Nb * NN * NN + (size_t)b * NN * NN * 2;
#pragma unroll
  for (int di = 0; di < TI; ++di)
#pragma unroll
    for (int dj = 0; dj < TJ; ++dj) {
      const int idx = (i0 + di) * NN + (j0 + dj);
      outM[idx] = t_lds[(di * TJ + dj) * NTHREADS + tid];
      reinterpret_cast<float2*>(outU)[idx] = make_float2(ux[di][dj], uy[di][dj]);
    }
}

extern "C" void kernel_launch(void* const* d_in, const int* in_sizes, int n_in,
                              void* d_out, int out_size, void* d_ws, size_t ws_size,
                              hipStream_t stream) {
  const float* M  = (const float*)d_in[0];
  const float* tv = (const float*)d_in[1];
  const int Nb = in_sizes[0] / (NN * NN);   // 8
  tv_kernel<<<dim3(Nb), dim3(NTHREADS), 0, stream>>>(M, tv, (float*)d_out, Nb);
}

// Round 8
// 3677.664 us; speedup vs baseline: 1.3730x; 1.0581x over previous
//
#include <hip/hip_runtime.h>
#include <math.h>

#define NIT 200
#define NN 128
#define TI 4
#define TJ 8
#define GI 32   // NN/TI
#define GJ 16   // NN/TJ
#define NTHREADS 512
#define NWAVES 8

__global__ __launch_bounds__(NTHREADS)
void tv_kernel(const float* __restrict__ Min, const float* __restrict__ tvr,
               float* __restrict__ out, int Nb)
{
  const float MUc = 0.25f;
  const int b   = blockIdx.x;
  const int tid = threadIdx.x;
  const int tx  = tid & (GJ - 1);   // 0..15
  const int ty  = tid >> 4;         // 0..31
  const int lane = tid & 63;
  const int wv   = tid >> 6;
  const int i0 = ty * TI;
  const int j0 = tx * TJ;

  // Full fields in LDS, tile layout [elem][tid]: bank = tid%32 (2 lanes/bank,
  // free). Neighbors are tid+16 (down) / tid+1 (right): same stride, free.
  __shared__ float m_lds[TI * TJ * NTHREADS];   // 64 KB, constant M field
  __shared__ float t_lds[TI * TJ * NTHREADS];   // 64 KB, scratch field t
  __shared__ float sTop [TJ][GI][GJ];           // 16 KB  (u bottom rows)
  __shared__ float sLeft[TI][GI][GJ];           //  8 KB  (u right cols)
  __shared__ float4 sRedA[2][NWAVES];           // parity-buffered reduce
  __shared__ float2 sRedB[2][NWAVES];
  // total ~152.5 KB -> 1 block/CU (grid is 8 blocks; costs nothing)

  const float r = tvr[0];

  // persistent register state: 4 arrays x 32 = 128 floats -> fits 128-reg cap
  float ux[TI][TJ], uy[TI][TJ], xx[TI][TJ], xy[TI][TJ];

  const float* Mb = Min + (size_t)b * NN * NN;
#pragma unroll
  for (int di = 0; di < TI; ++di) {
    float4 v0 = *reinterpret_cast<const float4*>(Mb + (i0 + di) * NN + j0);
    float4 v1 = *reinterpret_cast<const float4*>(Mb + (i0 + di) * NN + j0 + 4);
    m_lds[(di * TJ + 0) * NTHREADS + tid] = v0.x;
    m_lds[(di * TJ + 1) * NTHREADS + tid] = v0.y;
    m_lds[(di * TJ + 2) * NTHREADS + tid] = v0.z;
    m_lds[(di * TJ + 3) * NTHREADS + tid] = v0.w;
    m_lds[(di * TJ + 4) * NTHREADS + tid] = v1.x;
    m_lds[(di * TJ + 5) * NTHREADS + tid] = v1.y;
    m_lds[(di * TJ + 6) * NTHREADS + tid] = v1.z;
    m_lds[(di * TJ + 7) * NTHREADS + tid] = v1.w;
#pragma unroll
    for (int dj = 0; dj < TJ; ++dj) {
      ux[di][dj] = 0.f; uy[di][dj] = 0.f;
      xx[di][dj] = 0.f; xy[di][dj] = 0.f;
    }
  }
  __syncthreads();

  int par = 0;
  auto blk_red4 = [&](float v0, float v1, float v2, float v3) {
#pragma unroll
    for (int off = 32; off >= 1; off >>= 1) {
      v0 += __shfl_xor(v0, off, 64);
      v1 += __shfl_xor(v1, off, 64);
      v2 += __shfl_xor(v2, off, 64);
      v3 += __shfl_xor(v3, off, 64);
    }
    if (lane == 0) sRedA[par][wv] = make_float4(v0, v1, v2, v3);
    __syncthreads();
    float4 acc = make_float4(0.f, 0.f, 0.f, 0.f);
#pragma unroll
    for (int w = 0; w < NWAVES; ++w) {
      float4 q = sRedA[par][w];
      acc.x += q.x; acc.y += q.y; acc.z += q.z; acc.w += q.w;
    }
    par ^= 1;
    return acc;
  };
  // 6-value reduce: (s0,s1,psa0,psa1) + (pc0,pc1)
  auto blk_red6 = [&](float s0, float s1, float p0, float p1, float c0, float c1,
                      float4& o4, float2& o2) {
#pragma unroll
    for (int off = 32; off >= 1; off >>= 1) {
      s0 += __shfl_xor(s0, off, 64); s1 += __shfl_xor(s1, off, 64);
      p0 += __shfl_xor(p0, off, 64); p1 += __shfl_xor(p1, off, 64);
      c0 += __shfl_xor(c0, off, 64); c1 += __shfl_xor(c1, off, 64);
    }
    if (lane == 0) {
      sRedA[par][wv] = make_float4(s0, s1, p0, p1);
      sRedB[par][wv] = make_float2(c0, c1);
    }
    __syncthreads();
    float4 a4 = sRedA[par][0]; float2 a2 = sRedB[par][0];
#pragma unroll
    for (int w = 1; w < NWAVES; ++w) {
      float4 q = sRedA[par][w]; float2 h = sRedB[par][w];
      a4.x += q.x; a4.y += q.y; a4.z += q.z; a4.w += q.w;
      a2.x += h.x; a2.y += h.y;
    }
    par ^= 1;
    o4 = a4; o2 = a2;
  };

  // Duchi threshold solve with fused probe. Probe = (psa, pc) evaluated at
  // tp during the preceding field pass: psa = Sum max(a-tp,0), pc = count.
  // First Newton step comes free from the probe; loop rounds verify/refine.
  // Terminates on: fixed point, segment stability (count equal), or
  // relative step <= 1e-6 (theta error ~1e-6*theta, << output threshold).
  auto solve2 = [&](auto&& scan, float S0, float S1, float rad,
                    float psa0, float pc0, float tp0,
                    float psa1, float pc1, float tp1) -> float2 {
    const float invD = 1.f / 16384.f;
    float t0, t1; bool d0 = false, d1 = false;
    float np0 = -1.f, np1 = -1.f;
    if (S0 <= rad) { t0 = 0.f; d0 = true; }
    else {
      float lb = (S0 - rad) * invD;
      if (pc0 < 0.5f) t0 = lb;                       // probe theta above max
      else {
        float tn = tp0 + __fdividef(psa0 - rad, pc0);
        if (tn == tp0 || fabsf(tn - tp0) <= 1e-6f * tp0) { t0 = tn; d0 = true; }
        else { t0 = fmaxf(tn, lb); np0 = pc0; }
      }
    }
    if (S1 <= rad) { t1 = 0.f; d1 = true; }
    else {
      float lb = (S1 - rad) * invD;
      if (pc1 < 0.5f) t1 = lb;
      else {
        float tn = tp1 + __fdividef(psa1 - rad, pc1);
        if (tn == tp1 || fabsf(tn - tp1) <= 1e-6f * tp1) { t1 = tn; d1 = true; }
        else { t1 = fmaxf(tn, lb); np1 = pc1; }
      }
    }
    for (int k = 0; k < 40 && !(d0 && d1); ++k) {
      float sa0 = 0.f, c0 = 0.f, sa1 = 0.f, c1 = 0.f;
      scan(t0, t1, sa0, c0, sa1, c1);
      float4 rd = blk_red4(sa0, c0, sa1, c1);   // (sum0, cnt0, sum1, cnt1)
      if (!d0) {
        if (rd.y < 0.5f) { t0 = (S0 - rad) * invD; np0 = -1.f; }
        else {
          float tn = t0 + __fdividef(rd.x - rd.y * t0 - rad + rd.y * t0, rd.y); // dummy-free form below
          tn = __fdividef(rd.x, rd.y);           // rd.x = Sum a over active set
          tn = __fdividef(rd.x - rad, rd.y);
          if (rd.y == np0 || tn == t0 || fabsf(tn - t0) <= 1e-6f * t0) d0 = true;
          t0 = tn; np0 = rd.y;
        }
      }
      if (!d1) {
        if (rd.w < 0.5f) { t1 = (S1 - rad) * invD; np1 = -1.f; }
        else {
          float tn = __fdividef(rd.z - rad, rd.w);
          if (rd.w == np1 || tn == t1 || fabsf(tn - t1) <= 1e-6f * t1) d1 = true;
          t1 = tn; np1 = rd.w;
        }
      }
    }
    return make_float2(t0, t1);
  };

  // scan accumulates FULL sums over active set (a>t): sa = Sum a, c = count
  auto scanP1 = [&](float t0, float t1, float& sa0, float& c0, float& sa1, float& c1) {
#pragma unroll
    for (int di = 0; di < TI; ++di)
#pragma unroll
      for (int dj = 0; dj < TJ; ++dj) {
        float a0v = fabsf(ux[di][dj] - xx[di][dj]);
        float a1v = fabsf(uy[di][dj] - xy[di][dj]);
        if (a0v > t0) { sa0 += a0v; c0 += 1.f; }
        if (a1v > t1) { sa1 += a1v; c1 += 1.f; }
      }
  };
  auto scanP3 = [&](float t0, float t1, float& sa0, float& c0, float& sa1, float& c1) {
#pragma unroll
    for (int di = 0; di < TI; ++di)
#pragma unroll
      for (int dj = 0; dj < TJ; ++dj) {
        float a0v = fabsf(ux[di][dj]);
        float a1v = fabsf(uy[di][dj]);
        if (a0v > t0) { sa0 += a0v; c0 += 1.f; }
        if (a1v > t1) { sa1 += a1v; c1 += 1.f; }
      }
  };

  // div pass: t_lds = m - div(ux,uy); reads u halos, writes t_lds.
  auto div_pass = [&]() {
#pragma unroll
    for (int di = 0; di < TI; ++di) {
      const int i = i0 + di;
#pragma unroll
      for (int dj = 0; dj < TJ; ++dj) {
        const int j = j0 + dj;
        float up, lf;
        if (di > 0) up = ux[di - 1][dj];
        else { float h = sTop[dj][(ty > 0) ? ty - 1 : 0][tx]; up = (ty > 0) ? h : 0.f; }
        if (dj > 0) lf = uy[di][dj - 1];
        else { float h = sLeft[di][ty][(tx > 0) ? tx - 1 : 0]; lf = (tx > 0) ? h : 0.f; }
        float vxv = (i == NN - 1) ? 0.f : ux[di][dj];
        float vyv = (j == NN - 1) ? 0.f : uy[di][dj];
        float tt = m_lds[(di * TJ + dj) * NTHREADS + tid] - ((vxv - up) + (vyv - lf));
        t_lds[(di * TJ + dj) * NTHREADS + tid] = tt;
      }
    }
  };

  // grad pass: reads t_lds; consume(di,dj,gx,gy) with (gx,gy)=grad(t).
  auto grad_pass = [&](auto&& consume) {
#pragma unroll
    for (int di = 0; di < TI; ++di) {
      const int i = i0 + di;
#pragma unroll
      for (int dj = 0; dj < TJ; ++dj) {
        const int j = j0 + dj;
        float tc = t_lds[(di * TJ + dj) * NTHREADS + tid];
        float gx, gy;
        if (i == NN - 1) gx = 0.f;
        else {
          float dn = (di < TI - 1) ? t_lds[((di + 1) * TJ + dj) * NTHREADS + tid]
                                   : t_lds[(0 * TJ + dj) * NTHREADS + tid + GJ];
          gx = dn - tc;
        }
        if (j == NN - 1) gy = 0.f;
        else {
          float rt = (dj < TJ - 1) ? t_lds[(di * TJ + dj + 1) * NTHREADS + tid]
                                   : t_lds[(di * TJ + 0) * NTHREADS + tid + 1];
          gy = rt - tc;
        }
        consume(di, dj, gx, gy);
      }
    }
  };

  float A = 0.f;
  float h1x = 0.f, h1y = 0.f, h3x = 0.f, h3y = 0.f;   // previous thresholds
  // P1 carry: sums + probe (at h1) from prev P4b
  float S0p = 0.f, S1p = 0.f, q1s0 = 0.f, q1s1 = 0.f, q1c0 = 0.f, q1c1 = 0.f;
  float thx, thy;
  const float rad3 = r * (MUc * 0.5f);

#pragma unroll 1
  for (int it = 0; it < NIT; ++it) {
    const float a_ = 0.5f * (MUc + sqrtf(MUc * (MUc + 4.f * A)));

    // ---- P1 thresholds (A==0 at it==0 -> radius 0 -> identity)
    if (it == 0) { thx = INFINITY; thy = INFINITY; }
    else {
      float2 th = solve2(scanP1, S0p, S1p, r * A,
                         q1s0, q1c0, h1x, q1s1, q1c1, h1y);
      thx = th.x; thy = th.y; h1x = thx; h1y = thy;
    }

    // ---- P2a: y = cu*u + cv*clamp(u-xi, ±th); write y halos
    {
      const float inv = 1.f / (A + a_);
      const float cu = A * inv, cv = a_ * inv;
#pragma unroll
      for (int di = 0; di < TI; ++di)
#pragma unroll
        for (int dj = 0; dj < TJ; ++dj) {
          float vx = fminf(fmaxf(ux[di][dj] - xx[di][dj], -thx), thx);
          float vy = fminf(fmaxf(uy[di][dj] - xy[di][dj], -thy), thy);
          ux[di][dj] = ux[di][dj] * cu + vx * cv;
          uy[di][dj] = uy[di][dj] * cu + vy * cv;
        }
#pragma unroll
      for (int dj = 0; dj < TJ; ++dj) sTop[dj][ty][tx] = ux[TI - 1][dj];
#pragma unroll
      for (int di = 0; di < TI; ++di) sLeft[di][ty][tx] = uy[di][TJ - 1];
    }
    __syncthreads();
    div_pass();            // t = M - div(y)
    __syncthreads();

    // ---- P2b: u_pre = y - (mu/2) grad(t); fused P3 sums + probe at h3
    {
      float s0 = 0.f, s1 = 0.f, p0 = 0.f, p1 = 0.f, c0 = 0.f, c1 = 0.f;
      const float tp0 = h3x, tp1 = h3y;
      grad_pass([&](int di, int dj, float gx, float gy) {
        float nux = ux[di][dj] - 0.125f * gx;
        float nuy = uy[di][dj] - 0.125f * gy;
        ux[di][dj] = nux; uy[di][dj] = nuy;
        float a0 = fabsf(nux), a1 = fabsf(nuy);
        s0 += a0; s1 += a1;
        if (a0 > tp0) { p0 += a0 - tp0; c0 += 1.f; }
        if (a1 > tp1) { p1 += a1 - tp1; c1 += 1.f; }
      });
      float4 q4; float2 q2;
      blk_red6(s0, s1, p0, p1, c0, c1, q4, q2);

      // ---- P3: u = clamp(u_pre, ±th3)
      float2 th3 = solve2(scanP3, q4.x, q4.y, rad3,
                          q4.z, q2.x, tp0, q4.w, q2.y, tp1);
      thx = th3.x; thy = th3.y; h3x = thx; h3y = thy;
    }
    // ---- P4a: apply clamp; write u halos
#pragma unroll
    for (int di = 0; di < TI; ++di)
#pragma unroll
      for (int dj = 0; dj < TJ; ++dj) {
        ux[di][dj] = fminf(fmaxf(ux[di][dj], -thx), thx);
        uy[di][dj] = fminf(fmaxf(uy[di][dj], -thy), thy);
      }
#pragma unroll
    for (int dj = 0; dj < TJ; ++dj) sTop[dj][ty][tx] = ux[TI - 1][dj];
#pragma unroll
    for (int di = 0; di < TI; ++di) sLeft[di][ty][tx] = uy[di][TJ - 1];
    __syncthreads();
    div_pass();            // t = Mnew
    __syncthreads();

    // ---- P4b: xi += a*grad(Mnew); fused next-P1 sums + probe at h1
    {
      float s0 = 0.f, s1 = 0.f, p0 = 0.f, p1 = 0.f, c0 = 0.f, c1 = 0.f;
      const float tp0 = h1x, tp1 = h1y;
      grad_pass([&](int di, int dj, float gx, float gy) {
        xx[di][dj] += a_ * gx;
        xy[di][dj] += a_ * gy;
        float a0 = fabsf(ux[di][dj] - xx[di][dj]);
        float a1 = fabsf(uy[di][dj] - xy[di][dj]);
        s0 += a0; s1 += a1;
        if (a0 > tp0) { p0 += a0 - tp0; c0 += 1.f; }
        if (a1 > tp1) { p1 += a1 - tp1; c1 += 1.f; }
      });
      float4 q4; float2 q2;
      blk_red6(s0, s1, p0, p1, c0, c1, q4, q2);
      S0p = q4.x; S1p = q4.y; q1s0 = q4.z; q1s1 = q4.w; q1c0 = q2.x; q1c1 = q2.y;
    }
    A += a_;
  }

  // outputs: M1 = last Mnew (in t_lds), u interleaved (last-dim 2)
  float* outM = out + (size_t)b * NN * NN;
  float* outU = out + (size_t)Nb * NN * NN + (size_t)b * NN * NN * 2;
#pragma unroll
  for (int di = 0; di < TI; ++di)
#pragma unroll
    for (int dj = 0; dj < TJ; ++dj) {
      const int idx = (i0 + di) * NN + (j0 + dj);
      outM[idx] = t_lds[(di * TJ + dj) * NTHREADS + tid];
      reinterpret_cast<float2*>(outU)[idx] = make_float2(ux[di][dj], uy[di][dj]);
    }
}

extern "C" void kernel_launch(void* const* d_in, const int* in_sizes, int n_in,
                              void* d_out, int out_size, void* d_ws, size_t ws_size,
                              hipStream_t stream) {
  const float* M  = (const float*)d_in[0];
  const float* tv = (const float*)d_in[1];
  const int Nb = in_sizes[0] / (NN * NN);   // 8
  tv_kernel<<<dim3(Nb), dim3(NTHREADS), 0, stream>>>(M, tv, (float*)d_out, Nb);
}

// Round 9
// 3563.729 us; speedup vs baseline: 1.4169x; 1.0320x over previous
//
#include <hip/hip_runtime.h>
#include <math.h>

#define NIT 200
#define NN 128
#define TI 4
#define TJ 8
#define GI 32   // NN/TI
#define GJ 16   // NN/TJ
#define NTHREADS 512
#define NWAVES 8

typedef float f2 __attribute__((ext_vector_type(2)));

__global__ __launch_bounds__(NTHREADS)
void tv_kernel(const float* __restrict__ Min, const float* __restrict__ tvr,
               float* __restrict__ out, int Nb)
{
  const float MUc = 0.25f;
  const int b   = blockIdx.x;
  const int tid = threadIdx.x;
  const int tx  = tid & (GJ - 1);   // 0..15
  const int ty  = tid >> 4;         // 0..31
  const int lane = tid & 63;
  const int wv   = tid >> 6;
  const int i0 = ty * TI;
  const int j0 = tx * TJ;

  // Full fields in LDS, tile layout [elem][tid]: bank = tid%32 (2 lanes/bank,
  // free). Neighbors are tid+16 (down) / tid+1 (right): same stride, free.
  __shared__ float m_lds[TI * TJ * NTHREADS];   // 64 KB, constant M field
  __shared__ float t_lds[TI * TJ * NTHREADS];   // 64 KB, scratch field t
  __shared__ float sTop [TJ][GI][GJ];           // 16 KB  (u.x bottom rows)
  __shared__ float sLeft[TI][GI][GJ];           //  8 KB  (u.y right cols)
  __shared__ float4 sRedA[2][NWAVES];           // parity-buffered reduce
  __shared__ float2 sRedB[2][NWAVES];
  // total ~152.5 KB -> 1 block/CU (grid is 8 blocks; costs nothing)

  const float r = tvr[0];

  // persistent register state as packed (x,y) pairs: 2 arrays x 32 f2 = 128 regs
  f2 u[TI][TJ], xi[TI][TJ];

  const float* Mb = Min + (size_t)b * NN * NN;
#pragma unroll
  for (int di = 0; di < TI; ++di) {
    float4 v0 = *reinterpret_cast<const float4*>(Mb + (i0 + di) * NN + j0);
    float4 v1 = *reinterpret_cast<const float4*>(Mb + (i0 + di) * NN + j0 + 4);
    m_lds[(di * TJ + 0) * NTHREADS + tid] = v0.x;
    m_lds[(di * TJ + 1) * NTHREADS + tid] = v0.y;
    m_lds[(di * TJ + 2) * NTHREADS + tid] = v0.z;
    m_lds[(di * TJ + 3) * NTHREADS + tid] = v0.w;
    m_lds[(di * TJ + 4) * NTHREADS + tid] = v1.x;
    m_lds[(di * TJ + 5) * NTHREADS + tid] = v1.y;
    m_lds[(di * TJ + 6) * NTHREADS + tid] = v1.z;
    m_lds[(di * TJ + 7) * NTHREADS + tid] = v1.w;
#pragma unroll
    for (int dj = 0; dj < TJ; ++dj) {
      u[di][dj] = (f2)0.f; xi[di][dj] = (f2)0.f;
    }
  }
  __syncthreads();

  int par = 0;
  auto blk_red4 = [&](float v0, float v1, float v2, float v3) {
#pragma unroll
    for (int off = 32; off >= 1; off >>= 1) {
      v0 += __shfl_xor(v0, off, 64);
      v1 += __shfl_xor(v1, off, 64);
      v2 += __shfl_xor(v2, off, 64);
      v3 += __shfl_xor(v3, off, 64);
    }
    if (lane == 0) sRedA[par][wv] = make_float4(v0, v1, v2, v3);
    __syncthreads();
    float4 acc = make_float4(0.f, 0.f, 0.f, 0.f);
#pragma unroll
    for (int w = 0; w < NWAVES; ++w) {
      float4 q = sRedA[par][w];
      acc.x += q.x; acc.y += q.y; acc.z += q.z; acc.w += q.w;
    }
    par ^= 1;
    return acc;
  };
  // 6-value reduce: (s0,s1,psa0,psa1) + (pc0,pc1)
  auto blk_red6 = [&](float s0, float s1, float p0, float p1, float c0, float c1,
                      float4& o4, float2& o2) {
#pragma unroll
    for (int off = 32; off >= 1; off >>= 1) {
      s0 += __shfl_xor(s0, off, 64); s1 += __shfl_xor(s1, off, 64);
      p0 += __shfl_xor(p0, off, 64); p1 += __shfl_xor(p1, off, 64);
      c0 += __shfl_xor(c0, off, 64); c1 += __shfl_xor(c1, off, 64);
    }
    if (lane == 0) {
      sRedA[par][wv] = make_float4(s0, s1, p0, p1);
      sRedB[par][wv] = make_float2(c0, c1);
    }
    __syncthreads();
    float4 a4 = sRedA[par][0]; float2 a2 = sRedB[par][0];
#pragma unroll
    for (int w = 1; w < NWAVES; ++w) {
      float4 q = sRedA[par][w]; float2 h = sRedB[par][w];
      a4.x += q.x; a4.y += q.y; a4.z += q.z; a4.w += q.w;
      a2.x += h.x; a2.y += h.y;
    }
    par ^= 1;
    o4 = a4; o2 = a2;
  };

  // Duchi threshold solve with fused probe (psa = Sum max(a-tp,0), pc = count
  // at tp, reduced during the preceding field pass). First Newton step free;
  // loop rounds verify/refine. Terminates on fixed point, segment stability,
  // or relative step <= 1e-6.
  auto solve2 = [&](auto&& scan, float S0, float S1, float rad,
                    float psa0, float pc0, float tp0,
                    float psa1, float pc1, float tp1) -> float2 {
    const float invD = 1.f / 16384.f;
    float t0, t1; bool d0 = false, d1 = false;
    float np0 = -1.f, np1 = -1.f;
    if (S0 <= rad) { t0 = 0.f; d0 = true; }
    else {
      float lb = (S0 - rad) * invD;
      if (pc0 < 0.5f) t0 = lb;                       // probe theta above max
      else {
        float tn = tp0 + __fdividef(psa0 - rad, pc0);
        if (tn == tp0 || fabsf(tn - tp0) <= 1e-6f * tp0) { t0 = tn; d0 = true; }
        else { t0 = fmaxf(tn, lb); np0 = pc0; }
      }
    }
    if (S1 <= rad) { t1 = 0.f; d1 = true; }
    else {
      float lb = (S1 - rad) * invD;
      if (pc1 < 0.5f) t1 = lb;
      else {
        float tn = tp1 + __fdividef(psa1 - rad, pc1);
        if (tn == tp1 || fabsf(tn - tp1) <= 1e-6f * tp1) { t1 = tn; d1 = true; }
        else { t1 = fmaxf(tn, lb); np1 = pc1; }
      }
    }
    for (int k = 0; k < 40 && !(d0 && d1); ++k) {
      float sa0 = 0.f, c0 = 0.f, sa1 = 0.f, c1 = 0.f;
      scan(t0, t1, sa0, c0, sa1, c1);
      float4 rd = blk_red4(sa0, c0, sa1, c1);   // (sum0, cnt0, sum1, cnt1)
      if (!d0) {
        if (rd.y < 0.5f) { t0 = (S0 - rad) * invD; np0 = -1.f; }
        else {
          float tn = __fdividef(rd.x - rad, rd.y);
          if (rd.y == np0 || tn == t0 || fabsf(tn - t0) <= 1e-6f * t0) d0 = true;
          t0 = tn; np0 = rd.y;
        }
      }
      if (!d1) {
        if (rd.w < 0.5f) { t1 = (S1 - rad) * invD; np1 = -1.f; }
        else {
          float tn = __fdividef(rd.z - rad, rd.w);
          if (rd.w == np1 || tn == t1 || fabsf(tn - t1) <= 1e-6f * t1) d1 = true;
          t1 = tn; np1 = rd.w;
        }
      }
    }
    return make_float2(t0, t1);
  };

  // scan accumulates FULL sums over active set (a>t): sa = Sum a, c = count
  auto scanP1 = [&](float t0, float t1, float& sa0, float& c0, float& sa1, float& c1) {
#pragma unroll
    for (int di = 0; di < TI; ++di)
#pragma unroll
      for (int dj = 0; dj < TJ; ++dj) {
        f2 w = u[di][dj] - xi[di][dj];
        float a0v = fabsf(w.x);
        float a1v = fabsf(w.y);
        if (a0v > t0) { sa0 += a0v; c0 += 1.f; }
        if (a1v > t1) { sa1 += a1v; c1 += 1.f; }
      }
  };
  auto scanP3 = [&](float t0, float t1, float& sa0, float& c0, float& sa1, float& c1) {
#pragma unroll
    for (int di = 0; di < TI; ++di)
#pragma unroll
      for (int dj = 0; dj < TJ; ++dj) {
        float a0v = fabsf(u[di][dj].x);
        float a1v = fabsf(u[di][dj].y);
        if (a0v > t0) { sa0 += a0v; c0 += 1.f; }
        if (a1v > t1) { sa1 += a1v; c1 += 1.f; }
      }
  };

  // div pass: t_lds = m - div(u); reads u halos, writes t_lds.
  auto div_pass = [&]() {
#pragma unroll
    for (int di = 0; di < TI; ++di) {
      const int i = i0 + di;
#pragma unroll
      for (int dj = 0; dj < TJ; ++dj) {
        const int j = j0 + dj;
        float up, lf;
        if (di > 0) up = u[di - 1][dj].x;
        else { float h = sTop[dj][(ty > 0) ? ty - 1 : 0][tx]; up = (ty > 0) ? h : 0.f; }
        if (dj > 0) lf = u[di][dj - 1].y;
        else { float h = sLeft[di][ty][(tx > 0) ? tx - 1 : 0]; lf = (tx > 0) ? h : 0.f; }
        float vxv = (i == NN - 1) ? 0.f : u[di][dj].x;
        float vyv = (j == NN - 1) ? 0.f : u[di][dj].y;
        float tt = m_lds[(di * TJ + dj) * NTHREADS + tid] - ((vxv - up) + (vyv - lf));
        t_lds[(di * TJ + dj) * NTHREADS + tid] = tt;
      }
    }
  };

  // grad pass: reads t_lds; consume(di,dj,g) with g=(gx,gy)=grad(t).
  auto grad_pass = [&](auto&& consume) {
#pragma unroll
    for (int di = 0; di < TI; ++di) {
      const int i = i0 + di;
#pragma unroll
      for (int dj = 0; dj < TJ; ++dj) {
        const int j = j0 + dj;
        float tc = t_lds[(di * TJ + dj) * NTHREADS + tid];
        f2 g;
        if (i == NN - 1) g.x = 0.f;
        else {
          float dn = (di < TI - 1) ? t_lds[((di + 1) * TJ + dj) * NTHREADS + tid]
                                   : t_lds[(0 * TJ + dj) * NTHREADS + tid + GJ];
          g.x = dn - tc;
        }
        if (j == NN - 1) g.y = 0.f;
        else {
          float rt = (dj < TJ - 1) ? t_lds[(di * TJ + dj + 1) * NTHREADS + tid]
                                   : t_lds[(di * TJ + 0) * NTHREADS + tid + 1];
          g.y = rt - tc;
        }
        consume(di, dj, g);
      }
    }
  };

  float A = 0.f;
  float h1x = 0.f, h1y = 0.f, h3x = 0.f, h3y = 0.f;   // previous thresholds
  float S0p = 0.f, S1p = 0.f, q1s0 = 0.f, q1s1 = 0.f, q1c0 = 0.f, q1c1 = 0.f;
  float thx, thy;
  const float rad3 = r * (MUc * 0.5f);

#pragma unroll 1
  for (int it = 0; it < NIT; ++it) {
    const float a_ = 0.5f * (MUc + sqrtf(MUc * (MUc + 4.f * A)));

    // ---- P1 thresholds (A==0 at it==0 -> radius 0 -> identity)
    if (it == 0) { thx = INFINITY; thy = INFINITY; }
    else {
      float2 th = solve2(scanP1, S0p, S1p, r * A,
                         q1s0, q1c0, h1x, q1s1, q1c1, h1y);
      thx = th.x; thy = th.y; h1x = thx; h1y = thy;
    }

    // ---- P2a: y = cu*u + cv*clamp(u-xi, ±th); write y halos
    {
      const float inv = 1.f / (A + a_);
      const float cu = A * inv, cv = a_ * inv;
#pragma unroll
      for (int di = 0; di < TI; ++di)
#pragma unroll
        for (int dj = 0; dj < TJ; ++dj) {
          f2 w = u[di][dj] - xi[di][dj];                 // v_pk_add
          f2 v;
          v.x = __builtin_amdgcn_fmed3f(w.x, -thx, thx); // 1-inst clamp
          v.y = __builtin_amdgcn_fmed3f(w.y, -thy, thy);
          u[di][dj] = u[di][dj] * cu + v * cv;           // pk_mul + pk_fma
        }
#pragma unroll
      for (int dj = 0; dj < TJ; ++dj) sTop[dj][ty][tx] = u[TI - 1][dj].x;
#pragma unroll
      for (int di = 0; di < TI; ++di) sLeft[di][ty][tx] = u[di][TJ - 1].y;
    }
    __syncthreads();
    div_pass();            // t = M - div(y)
    __syncthreads();

    // ---- P2b: u_pre = y - (mu/2) grad(t); fused P3 sums + probe at h3
    {
      float s0 = 0.f, s1 = 0.f, p0 = 0.f, p1 = 0.f, c0 = 0.f, c1 = 0.f;
      const float tp0 = h3x, tp1 = h3y;
      grad_pass([&](int di, int dj, f2 g) {
        f2 nu = u[di][dj] - 0.125f * g;                  // pk_fma
        u[di][dj] = nu;
        float a0 = fabsf(nu.x), a1 = fabsf(nu.y);
        s0 += a0; s1 += a1;
        if (a0 > tp0) { p0 += a0 - tp0; c0 += 1.f; }
        if (a1 > tp1) { p1 += a1 - tp1; c1 += 1.f; }
      });
      float4 q4; float2 q2;
      blk_red6(s0, s1, p0, p1, c0, c1, q4, q2);

      // ---- P3: u = clamp(u_pre, ±th3)
      float2 th3 = solve2(scanP3, q4.x, q4.y, rad3,
                          q4.z, q2.x, tp0, q4.w, q2.y, tp1);
      thx = th3.x; thy = th3.y; h3x = thx; h3y = thy;
    }
    // ---- P4a: apply clamp; write u halos
#pragma unroll
    for (int di = 0; di < TI; ++di)
#pragma unroll
      for (int dj = 0; dj < TJ; ++dj) {
        u[di][dj].x = __builtin_amdgcn_fmed3f(u[di][dj].x, -thx, thx);
        u[di][dj].y = __builtin_amdgcn_fmed3f(u[di][dj].y, -thy, thy);
      }
#pragma unroll
    for (int dj = 0; dj < TJ; ++dj) sTop[dj][ty][tx] = u[TI - 1][dj].x;
#pragma unroll
    for (int di = 0; di < TI; ++di) sLeft[di][ty][tx] = u[di][TJ - 1].y;
    __syncthreads();
    div_pass();            // t = Mnew
    __syncthreads();

    // ---- P4b: xi += a*grad(Mnew); fused next-P1 sums + probe at h1
    {
      float s0 = 0.f, s1 = 0.f, p0 = 0.f, p1 = 0.f, c0 = 0.f, c1 = 0.f;
      const float tp0 = h1x, tp1 = h1y;
      grad_pass([&](int di, int dj, f2 g) {
        xi[di][dj] = xi[di][dj] + a_ * g;                // pk_fma
        f2 w = u[di][dj] - xi[di][dj];                   // pk_add
        float a0 = fabsf(w.x);
        float a1 = fabsf(w.y);
        s0 += a0; s1 += a1;
        if (a0 > tp0) { p0 += a0 - tp0; c0 += 1.f; }
        if (a1 > tp1) { p1 += a1 - tp1; c1 += 1.f; }
      });
      float4 q4; float2 q2;
      blk_red6(s0, s1, p0, p1, c0, c1, q4, q2);
      S0p = q4.x; S1p = q4.y; q1s0 = q4.z; q1s1 = q4.w; q1c0 = q2.x; q1c1 = q2.y;
    }
    A += a_;
  }

  // outputs: M1 = last Mnew (in t_lds), u interleaved (last-dim 2)
  float* outM = out + (size_t)b * NN * NN;
  float* outU = out + (size_t)Nb * NN * NN + (size_t)b * NN * NN * 2;
#pragma unroll
  for (int di = 0; di < TI; ++di)
#pragma unroll
    for (int dj = 0; dj < TJ; ++dj) {
      const int idx = (i0 + di) * NN + (j0 + dj);
      outM[idx] = t_lds[(di * TJ + dj) * NTHREADS + tid];
      reinterpret_cast<float2*>(outU)[idx] = make_float2(u[di][dj].x, u[di][dj].y);
    }
}

extern "C" void kernel_launch(void* const* d_in, const int* in_sizes, int n_in,
                              void* d_out, int out_size, void* d_ws, size_t ws_size,
                              hipStream_t stream) {
  const float* M  = (const float*)d_in[0];
  const float* tv = (const float*)d_in[1];
  const int Nb = in_sizes[0] / (NN * NN);   // 8
  tv_kernel<<<dim3(Nb), dim3(NTHREADS), 0, stream>>>(M, tv, (float*)d_out, Nb);
}

// Round 10
// 2297.801 us; speedup vs baseline: 2.1976x; 1.5509x over previous
//
#include <hip/hip_runtime.h>
#include <math.h>

#define NIT 200
#define NN 128
#define TI 4
#define TJ 8
#define GI 32   // NN/TI
#define GJ 16   // NN/TJ
#define NTHREADS 512
#define NWAVES 8

typedef float f2 __attribute__((ext_vector_type(2)));

__global__ __launch_bounds__(NTHREADS)
void tv_kernel(const float* __restrict__ Min, const float* __restrict__ tvr,
               float* __restrict__ out, int Nb)
{
  const float MUc = 0.25f;
  const int b   = blockIdx.x;
  const int tid = threadIdx.x;
  const int tx  = tid & (GJ - 1);   // 0..15
  const int ty  = tid >> 4;         // 0..31
  const int lane = tid & 63;
  const int wv   = tid >> 6;
  const int i0 = ty * TI;
  const int j0 = tx * TJ;

  // Full fields in LDS, tile layout [elem][tid]: bank = tid%32 (2 lanes/bank,
  // free). Neighbors are tid+16 (down) / tid+1 (right): same stride, free.
  __shared__ float m_lds[TI * TJ * NTHREADS];   // 64 KB, constant M field
  __shared__ float t_lds[TI * TJ * NTHREADS];   // 64 KB, scratch field t
  __shared__ float sTop [TJ][GI][GJ];           // 16 KB  (u.x bottom rows)
  __shared__ float sLeft[TI][GI][GJ];           //  8 KB  (u.y right cols)
  __shared__ float4 sRedA[2][NWAVES];           // parity-buffered reduce
  __shared__ float2 sRedB[2][NWAVES];
  // total ~152.5 KB -> 1 block/CU (grid is 8 blocks; costs nothing)

  const float r = tvr[0];

  // persistent register state as packed (x,y) pairs: 2 arrays x 32 f2 = 128 regs
  f2 u[TI][TJ], xi[TI][TJ];

  const float* Mb = Min + (size_t)b * NN * NN;
#pragma unroll
  for (int di = 0; di < TI; ++di) {
    float4 v0 = *reinterpret_cast<const float4*>(Mb + (i0 + di) * NN + j0);
    float4 v1 = *reinterpret_cast<const float4*>(Mb + (i0 + di) * NN + j0 + 4);
    m_lds[(di * TJ + 0) * NTHREADS + tid] = v0.x;
    m_lds[(di * TJ + 1) * NTHREADS + tid] = v0.y;
    m_lds[(di * TJ + 2) * NTHREADS + tid] = v0.z;
    m_lds[(di * TJ + 3) * NTHREADS + tid] = v0.w;
    m_lds[(di * TJ + 4) * NTHREADS + tid] = v1.x;
    m_lds[(di * TJ + 5) * NTHREADS + tid] = v1.y;
    m_lds[(di * TJ + 6) * NTHREADS + tid] = v1.z;
    m_lds[(di * TJ + 7) * NTHREADS + tid] = v1.w;
#pragma unroll
    for (int dj = 0; dj < TJ; ++dj) {
      u[di][dj] = (f2)0.f; xi[di][dj] = (f2)0.f;
    }
  }
  __syncthreads();

  int par = 0;
  auto blk_red4 = [&](float v0, float v1, float v2, float v3) {
#pragma unroll
    for (int off = 32; off >= 1; off >>= 1) {
      v0 += __shfl_xor(v0, off, 64);
      v1 += __shfl_xor(v1, off, 64);
      v2 += __shfl_xor(v2, off, 64);
      v3 += __shfl_xor(v3, off, 64);
    }
    if (lane == 0) sRedA[par][wv] = make_float4(v0, v1, v2, v3);
    __syncthreads();
    float4 acc = make_float4(0.f, 0.f, 0.f, 0.f);
#pragma unroll
    for (int w = 0; w < NWAVES; ++w) {
      float4 q = sRedA[par][w];
      acc.x += q.x; acc.y += q.y; acc.z += q.z; acc.w += q.w;
    }
    par ^= 1;
    return acc;
  };
  // 6-value reduce: (s0,s1,psa0,psa1) + (pc0,pc1)
  auto blk_red6 = [&](float s0, float s1, float p0, float p1, float c0, float c1,
                      float4& o4, float2& o2) {
#pragma unroll
    for (int off = 32; off >= 1; off >>= 1) {
      s0 += __shfl_xor(s0, off, 64); s1 += __shfl_xor(s1, off, 64);
      p0 += __shfl_xor(p0, off, 64); p1 += __shfl_xor(p1, off, 64);
      c0 += __shfl_xor(c0, off, 64); c1 += __shfl_xor(c1, off, 64);
    }
    if (lane == 0) {
      sRedA[par][wv] = make_float4(s0, s1, p0, p1);
      sRedB[par][wv] = make_float2(c0, c1);
    }
    __syncthreads();
    float4 a4 = sRedA[par][0]; float2 a2 = sRedB[par][0];
#pragma unroll
    for (int w = 1; w < NWAVES; ++w) {
      float4 q = sRedA[par][w]; float2 h = sRedB[par][w];
      a4.x += q.x; a4.y += q.y; a4.z += q.z; a4.w += q.w;
      a2.x += h.x; a2.y += h.y;
    }
    par ^= 1;
    o4 = a4; o2 = a2;
  };

  // Duchi threshold solve with fused PREDICTIVE probe: (psa, pc) evaluated at
  // the extrapolated threshold tp during the preceding field pass. The first
  // Newton step from the probe is free; with a good prediction it terminates
  // immediately (0 scan rounds). Terminates on fixed point, segment stability
  // (count unchanged -> step exact), or relative step <= 1e-4 (theta error
  // 1e-4*theta/iter; accumulated effect << 4.4e-2 output gate).
  auto solve2 = [&](auto&& scan, float S0, float S1, float rad,
                    float psa0, float pc0, float tp0,
                    float psa1, float pc1, float tp1) -> float2 {
    const float invD = 1.f / 16384.f;
    const float TOL = 1e-4f;
    float t0, t1; bool d0 = false, d1 = false;
    float np0 = -1.f, np1 = -1.f;
    if (S0 <= rad) { t0 = 0.f; d0 = true; }
    else {
      float lb = (S0 - rad) * invD;
      if (pc0 < 0.5f) t0 = lb;                       // probe theta above max
      else {
        float tn = tp0 + __fdividef(psa0 - rad, pc0);
        if (tn == tp0 || fabsf(tn - tp0) <= TOL * tp0) { t0 = tn; d0 = true; }
        else { t0 = fmaxf(tn, lb); np0 = pc0; }
      }
    }
    if (S1 <= rad) { t1 = 0.f; d1 = true; }
    else {
      float lb = (S1 - rad) * invD;
      if (pc1 < 0.5f) t1 = lb;
      else {
        float tn = tp1 + __fdividef(psa1 - rad, pc1);
        if (tn == tp1 || fabsf(tn - tp1) <= TOL * tp1) { t1 = tn; d1 = true; }
        else { t1 = fmaxf(tn, lb); np1 = pc1; }
      }
    }
    for (int k = 0; k < 40 && !(d0 && d1); ++k) {
      float sa0 = 0.f, c0 = 0.f, sa1 = 0.f, c1 = 0.f;
      scan(t0, t1, sa0, c0, sa1, c1);
      float4 rd = blk_red4(sa0, c0, sa1, c1);   // (sum0, cnt0, sum1, cnt1)
      if (!d0) {
        if (rd.y < 0.5f) { t0 = (S0 - rad) * invD; np0 = -1.f; }
        else {
          float tn = __fdividef(rd.x - rad, rd.y);
          if (rd.y == np0 || tn == t0 || fabsf(tn - t0) <= TOL * t0) d0 = true;
          t0 = tn; np0 = rd.y;
        }
      }
      if (!d1) {
        if (rd.w < 0.5f) { t1 = (S1 - rad) * invD; np1 = -1.f; }
        else {
          float tn = __fdividef(rd.z - rad, rd.w);
          if (rd.w == np1 || tn == t1 || fabsf(tn - t1) <= TOL * t1) d1 = true;
          t1 = tn; np1 = rd.w;
        }
      }
    }
    return make_float2(t0, t1);
  };

  // scan accumulates FULL sums over active set (a>t): sa = Sum a, c = count
  auto scanP1 = [&](float t0, float t1, float& sa0, float& c0, float& sa1, float& c1) {
#pragma unroll
    for (int di = 0; di < TI; ++di)
#pragma unroll
      for (int dj = 0; dj < TJ; ++dj) {
        f2 w = u[di][dj] - xi[di][dj];
        float a0v = fabsf(w.x);
        float a1v = fabsf(w.y);
        if (a0v > t0) { sa0 += a0v; c0 += 1.f; }
        if (a1v > t1) { sa1 += a1v; c1 += 1.f; }
      }
  };
  auto scanP3 = [&](float t0, float t1, float& sa0, float& c0, float& sa1, float& c1) {
#pragma unroll
    for (int di = 0; di < TI; ++di)
#pragma unroll
      for (int dj = 0; dj < TJ; ++dj) {
        float a0v = fabsf(u[di][dj].x);
        float a1v = fabsf(u[di][dj].y);
        if (a0v > t0) { sa0 += a0v; c0 += 1.f; }
        if (a1v > t1) { sa1 += a1v; c1 += 1.f; }
      }
  };

  // div pass: t_lds = m - div(u); reads u halos, writes t_lds.
  auto div_pass = [&]() {
#pragma unroll
    for (int di = 0; di < TI; ++di) {
      const int i = i0 + di;
#pragma unroll
      for (int dj = 0; dj < TJ; ++dj) {
        const int j = j0 + dj;
        float up, lf;
        if (di > 0) up = u[di - 1][dj].x;
        else { float h = sTop[dj][(ty > 0) ? ty - 1 : 0][tx]; up = (ty > 0) ? h : 0.f; }
        if (dj > 0) lf = u[di][dj - 1].y;
        else { float h = sLeft[di][ty][(tx > 0) ? tx - 1 : 0]; lf = (tx > 0) ? h : 0.f; }
        float vxv = (i == NN - 1) ? 0.f : u[di][dj].x;
        float vyv = (j == NN - 1) ? 0.f : u[di][dj].y;
        float tt = m_lds[(di * TJ + dj) * NTHREADS + tid] - ((vxv - up) + (vyv - lf));
        t_lds[(di * TJ + dj) * NTHREADS + tid] = tt;
      }
    }
  };

  // grad pass: reads t_lds; consume(di,dj,g) with g=(gx,gy)=grad(t).
  auto grad_pass = [&](auto&& consume) {
#pragma unroll
    for (int di = 0; di < TI; ++di) {
      const int i = i0 + di;
#pragma unroll
      for (int dj = 0; dj < TJ; ++dj) {
        const int j = j0 + dj;
        float tc = t_lds[(di * TJ + dj) * NTHREADS + tid];
        f2 g;
        if (i == NN - 1) g.x = 0.f;
        else {
          float dn = (di < TI - 1) ? t_lds[((di + 1) * TJ + dj) * NTHREADS + tid]
                                   : t_lds[(0 * TJ + dj) * NTHREADS + tid + GJ];
          g.x = dn - tc;
        }
        if (j == NN - 1) g.y = 0.f;
        else {
          float rt = (dj < TJ - 1) ? t_lds[(di * TJ + dj + 1) * NTHREADS + tid]
                                   : t_lds[(di * TJ + 0) * NTHREADS + tid + 1];
          g.y = rt - tc;
        }
        consume(di, dj, g);
      }
    }
  };

  float A = 0.f;
  // thresholds + last deltas (for linear extrapolation of the probe point)
  float h1x = 0.f, h1y = 0.f, d1x = 0.f, d1y = 0.f;
  float h3x = 0.f, h3y = 0.f, d3x = 0.f, d3y = 0.f;
  // P1 carry: sums + probe (at t1p) from prev P4b
  float S0p = 0.f, S1p = 0.f, q1s0 = 0.f, q1s1 = 0.f, q1c0 = 0.f, q1c1 = 0.f;
  float t1p0 = 0.f, t1p1 = 0.f;
  float thx, thy;
  const float rad3 = r * (MUc * 0.5f);

#pragma unroll 1
  for (int it = 0; it < NIT; ++it) {
    const float a_ = 0.5f * (MUc + sqrtf(MUc * (MUc + 4.f * A)));

    // ---- P1 thresholds (A==0 at it==0 -> radius 0 -> identity)
    if (it == 0) { thx = INFINITY; thy = INFINITY; }
    else {
      float2 th = solve2(scanP1, S0p, S1p, r * A,
                         q1s0, q1c0, t1p0, q1s1, q1c1, t1p1);
      thx = th.x; thy = th.y;
      d1x = thx - h1x; d1y = thy - h1y;
      h1x = thx; h1y = thy;
    }

    // ---- P2a: y = cu*u + cv*clamp(u-xi, ±th); write y halos
    {
      const float inv = 1.f / (A + a_);
      const float cu = A * inv, cv = a_ * inv;
#pragma unroll
      for (int di = 0; di < TI; ++di)
#pragma unroll
        for (int dj = 0; dj < TJ; ++dj) {
          f2 w = u[di][dj] - xi[di][dj];                 // v_pk_add
          f2 v;
          v.x = __builtin_amdgcn_fmed3f(w.x, -thx, thx); // 1-inst clamp
          v.y = __builtin_amdgcn_fmed3f(w.y, -thy, thy);
          u[di][dj] = u[di][dj] * cu + v * cv;           // pk_mul + pk_fma
        }
#pragma unroll
      for (int dj = 0; dj < TJ; ++dj) sTop[dj][ty][tx] = u[TI - 1][dj].x;
#pragma unroll
      for (int di = 0; di < TI; ++di) sLeft[di][ty][tx] = u[di][TJ - 1].y;
    }
    __syncthreads();
    div_pass();            // t = M - div(y)
    __syncthreads();

    // ---- P2b: u_pre = y - (mu/2) grad(t); fused P3 sums + predictive probe
    {
      float s0 = 0.f, s1 = 0.f, p0 = 0.f, p1 = 0.f, c0 = 0.f, c1 = 0.f;
      const float tp0 = fmaxf(0.f, h3x + d3x);   // extrapolated theta3
      const float tp1 = fmaxf(0.f, h3y + d3y);
      grad_pass([&](int di, int dj, f2 g) {
        f2 nu = u[di][dj] - 0.125f * g;                  // pk_fma
        u[di][dj] = nu;
        float a0 = fabsf(nu.x), a1 = fabsf(nu.y);
        s0 += a0; s1 += a1;
        if (a0 > tp0) { p0 += a0 - tp0; c0 += 1.f; }
        if (a1 > tp1) { p1 += a1 - tp1; c1 += 1.f; }
      });
      float4 q4; float2 q2;
      blk_red6(s0, s1, p0, p1, c0, c1, q4, q2);

      // ---- P3: u = clamp(u_pre, ±th3)
      float2 th3 = solve2(scanP3, q4.x, q4.y, rad3,
                          q4.z, q2.x, tp0, q4.w, q2.y, tp1);
      thx = th3.x; thy = th3.y;
      d3x = thx - h3x; d3y = thy - h3y;
      h3x = thx; h3y = thy;
    }
    // ---- P4a: apply clamp; write u halos
#pragma unroll
    for (int di = 0; di < TI; ++di)
#pragma unroll
      for (int dj = 0; dj < TJ; ++dj) {
        u[di][dj].x = __builtin_amdgcn_fmed3f(u[di][dj].x, -thx, thx);
        u[di][dj].y = __builtin_amdgcn_fmed3f(u[di][dj].y, -thy, thy);
      }
#pragma unroll
    for (int dj = 0; dj < TJ; ++dj) sTop[dj][ty][tx] = u[TI - 1][dj].x;
#pragma unroll
    for (int di = 0; di < TI; ++di) sLeft[di][ty][tx] = u[di][TJ - 1].y;
    __syncthreads();
    div_pass();            // t = Mnew
    __syncthreads();

    // ---- P4b: xi += a*grad(Mnew); fused next-P1 sums + predictive probe
    {
      float s0 = 0.f, s1 = 0.f, p0 = 0.f, p1 = 0.f, c0 = 0.f, c1 = 0.f;
      t1p0 = fmaxf(0.f, h1x + d1x);              // extrapolated theta1
      t1p1 = fmaxf(0.f, h1y + d1y);
      const float tp0 = t1p0, tp1 = t1p1;
      grad_pass([&](int di, int dj, f2 g) {
        xi[di][dj] = xi[di][dj] + a_ * g;                // pk_fma
        f2 w = u[di][dj] - xi[di][dj];                   // pk_add
        float a0 = fabsf(w.x);
        float a1 = fabsf(w.y);
        s0 += a0; s1 += a1;
        if (a0 > tp0) { p0 += a0 - tp0; c0 += 1.f; }
        if (a1 > tp1) { p1 += a1 - tp1; c1 += 1.f; }
      });
      float4 q4; float2 q2;
      blk_red6(s0, s1, p0, p1, c0, c1, q4, q2);
      S0p = q4.x; S1p = q4.y; q1s0 = q4.z; q1s1 = q4.w; q1c0 = q2.x; q1c1 = q2.y;
    }
    A += a_;
  }

  // outputs: M1 = last Mnew (in t_lds), u interleaved (last-dim 2)
  float* outM = out + (size_t)b * NN * NN;
  float* outU = out + (size_t)Nb * NN * NN + (size_t)b * NN * NN * 2;
#pragma unroll
  for (int di = 0; di < TI; ++di)
#pragma unroll
    for (int dj = 0; dj < TJ; ++dj) {
      const int idx = (i0 + di) * NN + (j0 + dj);
      outM[idx] = t_lds[(di * TJ + dj) * NTHREADS + tid];
      reinterpret_cast<float2*>(outU)[idx] = make_float2(u[di][dj].x, u[di][dj].y);
    }
}

extern "C" void kernel_launch(void* const* d_in, const int* in_sizes, int n_in,
                              void* d_out, int out_size, void* d_ws, size_t ws_size,
                              hipStream_t stream) {
  const float* M  = (const float*)d_in[0];
  const float* tv = (const float*)d_in[1];
  const int Nb = in_sizes[0] / (NN * NN);   // 8
  tv_kernel<<<dim3(Nb), dim3(NTHREADS), 0, stream>>>(M, tv, (float*)d_out, Nb);
}

// Round 11
// 2205.356 us; speedup vs baseline: 2.2897x; 1.0419x over previous
//
#include <hip/hip_runtime.h>
#include <math.h>

#define NIT 200
#define NN 128
#define TI 4
#define TJ 8
#define GI 32   // NN/TI
#define GJ 16   // NN/TJ
#define NTHREADS 512
#define NWAVES 8

typedef float f2 __attribute__((ext_vector_type(2)));

__global__ __launch_bounds__(NTHREADS)
void tv_kernel(const float* __restrict__ Min, const float* __restrict__ tvr,
               float* __restrict__ out, int Nb)
{
  const float MUc = 0.25f;
  const int b   = blockIdx.x;
  const int tid = threadIdx.x;
  const int tx  = tid & (GJ - 1);   // 0..15
  const int ty  = tid >> 4;         // 0..31
  const int lane = tid & 63;
  const int wv   = tid >> 6;
  const int i0 = ty * TI;
  const int j0 = tx * TJ;

  // Fields in LDS as float2 PAIRS [pair][tid]: b64 access, bank-uniform
  // stride (8B/lane -> 2 banks/lane, no pathological conflicts).
  __shared__ float2 m2_lds[(TI * TJ / 2) * NTHREADS];  // 64 KB, constant M
  __shared__ float2 t2_lds[(TI * TJ / 2) * NTHREADS];  // 64 KB, scratch t
  __shared__ float sTop [TJ][GI][GJ];           // 16 KB  (u.x bottom rows)
  __shared__ float sLeft[TI][GI][GJ];           //  8 KB  (u.y right cols)
  __shared__ float4 sRedA[2][NWAVES];           // parity-buffered reduce
  __shared__ float2 sRedB[2][NWAVES];
  // total ~152.5 KB -> 1 block/CU

  const float r = tvr[0];
  // boundary masks (hoisted; applied only at di==TI-1 / dj==TJ-1)
  const float mx = (ty == GI - 1) ? 0.f : 1.f;
  const float my = (tx == GJ - 1) ? 0.f : 1.f;

  // persistent register state: 2 arrays x 32 f2 = 128 regs
  f2 u[TI][TJ], xi[TI][TJ];

  const float* Mb = Min + (size_t)b * NN * NN;
#pragma unroll
  for (int di = 0; di < TI; ++di) {
    float4 v0 = *reinterpret_cast<const float4*>(Mb + (i0 + di) * NN + j0);
    float4 v1 = *reinterpret_cast<const float4*>(Mb + (i0 + di) * NN + j0 + 4);
    m2_lds[(di * 4 + 0) * NTHREADS + tid] = make_float2(v0.x, v0.y);
    m2_lds[(di * 4 + 1) * NTHREADS + tid] = make_float2(v0.z, v0.w);
    m2_lds[(di * 4 + 2) * NTHREADS + tid] = make_float2(v1.x, v1.y);
    m2_lds[(di * 4 + 3) * NTHREADS + tid] = make_float2(v1.z, v1.w);
#pragma unroll
    for (int dj = 0; dj < TJ; ++dj) {
      u[di][dj] = (f2)0.f; xi[di][dj] = (f2)0.f;
    }
  }
  __syncthreads();

  int par = 0;
  auto blk_red4 = [&](float v0, float v1, float v2, float v3) {
#pragma unroll
    for (int off = 32; off >= 1; off >>= 1) {
      v0 += __shfl_xor(v0, off, 64);
      v1 += __shfl_xor(v1, off, 64);
      v2 += __shfl_xor(v2, off, 64);
      v3 += __shfl_xor(v3, off, 64);
    }
    if (lane == 0) sRedA[par][wv] = make_float4(v0, v1, v2, v3);
    __syncthreads();
    float4 acc = make_float4(0.f, 0.f, 0.f, 0.f);
#pragma unroll
    for (int w = 0; w < NWAVES; ++w) {
      float4 q = sRedA[par][w];
      acc.x += q.x; acc.y += q.y; acc.z += q.z; acc.w += q.w;
    }
    par ^= 1;
    return acc;
  };
  // 6-value reduce: (s0,s1,psa0,psa1) + (pc0,pc1)
  auto blk_red6 = [&](float s0, float s1, float p0, float p1, float c0, float c1,
                      float4& o4, float2& o2) {
#pragma unroll
    for (int off = 32; off >= 1; off >>= 1) {
      s0 += __shfl_xor(s0, off, 64); s1 += __shfl_xor(s1, off, 64);
      p0 += __shfl_xor(p0, off, 64); p1 += __shfl_xor(p1, off, 64);
      c0 += __shfl_xor(c0, off, 64); c1 += __shfl_xor(c1, off, 64);
    }
    if (lane == 0) {
      sRedA[par][wv] = make_float4(s0, s1, p0, p1);
      sRedB[par][wv] = make_float2(c0, c1);
    }
    __syncthreads();
    float4 a4 = sRedA[par][0]; float2 a2 = sRedB[par][0];
#pragma unroll
    for (int w = 1; w < NWAVES; ++w) {
      float4 q = sRedA[par][w]; float2 h = sRedB[par][w];
      a4.x += q.x; a4.y += q.y; a4.z += q.z; a4.w += q.w;
      a2.x += h.x; a2.y += h.y;
    }
    par ^= 1;
    o4 = a4; o2 = a2;
  };

  // Duchi threshold solve with fused PREDICTIVE probe (see r10). Terminates on
  // fixed point, segment stability, or relative step <= 1e-4.
  auto solve2 = [&](auto&& scan, float S0, float S1, float rad,
                    float psa0, float pc0, float tp0,
                    float psa1, float pc1, float tp1) -> float2 {
    const float invD = 1.f / 16384.f;
    const float TOL = 1e-4f;
    float t0, t1; bool d0 = false, d1 = false;
    float np0 = -1.f, np1 = -1.f;
    if (S0 <= rad) { t0 = 0.f; d0 = true; }
    else {
      float lb = (S0 - rad) * invD;
      if (pc0 < 0.5f) t0 = lb;
      else {
        float tn = tp0 + __fdividef(psa0 - rad, pc0);
        if (tn == tp0 || fabsf(tn - tp0) <= TOL * tp0) { t0 = tn; d0 = true; }
        else { t0 = fmaxf(tn, lb); np0 = pc0; }
      }
    }
    if (S1 <= rad) { t1 = 0.f; d1 = true; }
    else {
      float lb = (S1 - rad) * invD;
      if (pc1 < 0.5f) t1 = lb;
      else {
        float tn = tp1 + __fdividef(psa1 - rad, pc1);
        if (tn == tp1 || fabsf(tn - tp1) <= TOL * tp1) { t1 = tn; d1 = true; }
        else { t1 = fmaxf(tn, lb); np1 = pc1; }
      }
    }
    for (int k = 0; k < 40 && !(d0 && d1); ++k) {
      float sa0 = 0.f, c0 = 0.f, sa1 = 0.f, c1 = 0.f;
      scan(t0, t1, sa0, c0, sa1, c1);
      float4 rd = blk_red4(sa0, c0, sa1, c1);
      if (!d0) {
        if (rd.y < 0.5f) { t0 = (S0 - rad) * invD; np0 = -1.f; }
        else {
          float tn = __fdividef(rd.x - rad, rd.y);
          if (rd.y == np0 || tn == t0 || fabsf(tn - t0) <= TOL * t0) d0 = true;
          t0 = tn; np0 = rd.y;
        }
      }
      if (!d1) {
        if (rd.w < 0.5f) { t1 = (S1 - rad) * invD; np1 = -1.f; }
        else {
          float tn = __fdividef(rd.z - rad, rd.w);
          if (rd.w == np1 || tn == t1 || fabsf(tn - t1) <= TOL * t1) d1 = true;
          t1 = tn; np1 = rd.w;
        }
      }
    }
    return make_float2(t0, t1);
  };

  auto scanP1 = [&](float t0, float t1, float& sa0, float& c0, float& sa1, float& c1) {
#pragma unroll
    for (int di = 0; di < TI; ++di)
#pragma unroll
      for (int dj = 0; dj < TJ; ++dj) {
        f2 w = u[di][dj] - xi[di][dj];
        float a0v = fabsf(w.x);
        float a1v = fabsf(w.y);
        if (a0v > t0) { sa0 += a0v; c0 += 1.f; }
        if (a1v > t1) { sa1 += a1v; c1 += 1.f; }
      }
  };
  auto scanP3 = [&](float t0, float t1, float& sa0, float& c0, float& sa1, float& c1) {
#pragma unroll
    for (int di = 0; di < TI; ++di)
#pragma unroll
      for (int dj = 0; dj < TJ; ++dj) {
        float a0v = fabsf(u[di][dj].x);
        float a1v = fabsf(u[di][dj].y);
        if (a0v > t0) { sa0 += a0v; c0 += 1.f; }
        if (a1v > t1) { sa1 += a1v; c1 += 1.f; }
      }
  };

  // div pass: t = m - div(u); pairwise b64 reads of m, b64 writes of t.
  auto div_pass = [&]() {
#pragma unroll
    for (int di = 0; di < TI; ++di) {
#pragma unroll
      for (int q2 = 0; q2 < 4; ++q2) {
        float2 mm = m2_lds[(di * 4 + q2) * NTHREADS + tid];
        float tt0, tt1;
        {
          const int dj = 2 * q2;
          float up = (di > 0) ? u[di - 1][dj].x
                              : ((ty > 0) ? sTop[dj][(ty > 0) ? ty - 1 : 0][tx] : 0.f);
          float lf = (dj > 0) ? u[di][dj - 1].y
                              : ((tx > 0) ? sLeft[di][ty][(tx > 0) ? tx - 1 : 0] : 0.f);
          float vx = u[di][dj].x; if (di == TI - 1) vx *= mx;
          float vy = u[di][dj].y;                      // dj even < 7
          tt0 = mm.x - ((vx - up) + (vy - lf));
        }
        {
          const int dj = 2 * q2 + 1;
          float up = (di > 0) ? u[di - 1][dj].x
                              : ((ty > 0) ? sTop[dj][(ty > 0) ? ty - 1 : 0][tx] : 0.f);
          float lf = u[di][dj - 1].y;
          float vx = u[di][dj].x; if (di == TI - 1) vx *= mx;
          float vy = u[di][dj].y; if (dj == TJ - 1) vy *= my;
          tt1 = mm.y - ((vx - up) + (vy - lf));
        }
        t2_lds[(di * 4 + q2) * NTHREADS + tid] = make_float2(tt0, tt1);
      }
    }
  };

  // grad pass: strip-walk with 2-pair rolling window. Per strip (dj pair):
  // 1 + TI b64 pair loads + TI b32 right-neighbor loads. consume(di,dj,g).
  auto grad_pass = [&](auto&& consume) {
#pragma unroll
    for (int q2 = 0; q2 < 4; ++q2) {
      float2 cur = t2_lds[q2 * NTHREADS + tid];
#pragma unroll
      for (int di = 0; di < TI; ++di) {
        float2 nxt;
        if (di < TI - 1) nxt = t2_lds[((di + 1) * 4 + q2) * NTHREADS + tid];
        else nxt = t2_lds[q2 * NTHREADS + tid + ((ty < GI - 1) ? GJ : 0)];
        float rt1;
        if (q2 < 3) rt1 = t2_lds[(di * 4 + q2 + 1) * NTHREADS + tid].x;
        else rt1 = t2_lds[(di * 4) * NTHREADS + tid + ((tx < GJ - 1) ? 1 : 0)].x;
        {
          f2 g;                              // dj = 2*q2 (even, < 7)
          g.x = nxt.x - cur.x; if (di == TI - 1) g.x *= mx;
          g.y = cur.y - cur.x;
          consume(di, 2 * q2, g);
        }
        {
          f2 g;                              // dj = 2*q2+1
          g.x = nxt.y - cur.y; if (di == TI - 1) g.x *= mx;
          g.y = rt1 - cur.y;   if (q2 == 3) g.y *= my;
          consume(di, 2 * q2 + 1, g);
        }
        cur = nxt;
      }
    }
  };

  float A = 0.f;
  float h1x = 0.f, h1y = 0.f, d1x = 0.f, d1y = 0.f;
  float h3x = 0.f, h3y = 0.f, d3x = 0.f, d3y = 0.f;
  float S0p = 0.f, S1p = 0.f, q1s0 = 0.f, q1s1 = 0.f, q1c0 = 0.f, q1c1 = 0.f;
  float t1p0 = 0.f, t1p1 = 0.f;
  float thx, thy;
  const float rad3 = r * (MUc * 0.5f);

#pragma unroll 1
  for (int it = 0; it < NIT; ++it) {
    const float a_ = 0.5f * (MUc + sqrtf(MUc * (MUc + 4.f * A)));

    // ---- P1 thresholds
    if (it == 0) { thx = INFINITY; thy = INFINITY; }
    else {
      float2 th = solve2(scanP1, S0p, S1p, r * A,
                         q1s0, q1c0, t1p0, q1s1, q1c1, t1p1);
      thx = th.x; thy = th.y;
      d1x = thx - h1x; d1y = thy - h1y;
      h1x = thx; h1y = thy;
    }

    // ---- P2a: y = cu*u + cv*clamp(u-xi, ±th); write y halos
    {
      const float inv = 1.f / (A + a_);
      const float cu = A * inv, cv = a_ * inv;
#pragma unroll
      for (int di = 0; di < TI; ++di)
#pragma unroll
        for (int dj = 0; dj < TJ; ++dj) {
          f2 w = u[di][dj] - xi[di][dj];
          f2 v;
          v.x = __builtin_amdgcn_fmed3f(w.x, -thx, thx);
          v.y = __builtin_amdgcn_fmed3f(w.y, -thy, thy);
          u[di][dj] = u[di][dj] * cu + v * cv;
        }
#pragma unroll
      for (int dj = 0; dj < TJ; ++dj) sTop[dj][ty][tx] = u[TI - 1][dj].x;
#pragma unroll
      for (int di = 0; di < TI; ++di) sLeft[di][ty][tx] = u[di][TJ - 1].y;
    }
    __syncthreads();
    div_pass();            // t = M - div(y)
    __syncthreads();

    // ---- P2b: u_pre = y - (mu/2) grad(t); fused P3 sums + predictive probe
    {
      float s0 = 0.f, s1 = 0.f, p0 = 0.f, p1 = 0.f, c0 = 0.f, c1 = 0.f;
      const float tp0 = fmaxf(0.f, h3x + d3x);
      const float tp1 = fmaxf(0.f, h3y + d3y);
      grad_pass([&](int di, int dj, f2 g) {
        f2 nu = u[di][dj] - 0.125f * g;
        u[di][dj] = nu;
        float a0 = fabsf(nu.x), a1 = fabsf(nu.y);
        s0 += a0; s1 += a1;
        if (a0 > tp0) { p0 += a0 - tp0; c0 += 1.f; }
        if (a1 > tp1) { p1 += a1 - tp1; c1 += 1.f; }
      });
      float4 q4; float2 q2;
      blk_red6(s0, s1, p0, p1, c0, c1, q4, q2);

      float2 th3 = solve2(scanP3, q4.x, q4.y, rad3,
                          q4.z, q2.x, tp0, q4.w, q2.y, tp1);
      thx = th3.x; thy = th3.y;
      d3x = thx - h3x; d3y = thy - h3y;
      h3x = thx; h3y = thy;
    }
    // ---- P4a: apply clamp; write u halos
#pragma unroll
    for (int di = 0; di < TI; ++di)
#pragma unroll
      for (int dj = 0; dj < TJ; ++dj) {
        u[di][dj].x = __builtin_amdgcn_fmed3f(u[di][dj].x, -thx, thx);
        u[di][dj].y = __builtin_amdgcn_fmed3f(u[di][dj].y, -thy, thy);
      }
#pragma unroll
    for (int dj = 0; dj < TJ; ++dj) sTop[dj][ty][tx] = u[TI - 1][dj].x;
#pragma unroll
    for (int di = 0; di < TI; ++di) sLeft[di][ty][tx] = u[di][TJ - 1].y;
    __syncthreads();
    div_pass();            // t = Mnew
    __syncthreads();

    // ---- P4b: xi += a*grad(Mnew); fused next-P1 sums + predictive probe
    {
      float s0 = 0.f, s1 = 0.f, p0 = 0.f, p1 = 0.f, c0 = 0.f, c1 = 0.f;
      t1p0 = fmaxf(0.f, h1x + d1x);
      t1p1 = fmaxf(0.f, h1y + d1y);
      const float tp0 = t1p0, tp1 = t1p1;
      grad_pass([&](int di, int dj, f2 g) {
        xi[di][dj] = xi[di][dj] + a_ * g;
        f2 w = u[di][dj] - xi[di][dj];
        float a0 = fabsf(w.x);
        float a1 = fabsf(w.y);
        s0 += a0; s1 += a1;
        if (a0 > tp0) { p0 += a0 - tp0; c0 += 1.f; }
        if (a1 > tp1) { p1 += a1 - tp1; c1 += 1.f; }
      });
      float4 q4; float2 q2;
      blk_red6(s0, s1, p0, p1, c0, c1, q4, q2);
      S0p = q4.x; S1p = q4.y; q1s0 = q4.z; q1s1 = q4.w; q1c0 = q2.x; q1c1 = q2.y;
    }
    A += a_;
  }

  // outputs: M1 = last Mnew (in t2_lds), u interleaved (last-dim 2)
  float* outM = out + (size_t)b * NN * NN;
  float* outU = out + (size_t)Nb * NN * NN + (size_t)b * NN * NN * 2;
#pragma unroll
  for (int di = 0; di < TI; ++di)
#pragma unroll
    for (int q2 = 0; q2 < 4; ++q2) {
      float2 tp = t2_lds[(di * 4 + q2) * NTHREADS + tid];
      const int idx0 = (i0 + di) * NN + (j0 + 2 * q2);
      outM[idx0]     = tp.x;
      outM[idx0 + 1] = tp.y;
      reinterpret_cast<float2*>(outU)[idx0]     = make_float2(u[di][2 * q2].x,     u[di][2 * q2].y);
      reinterpret_cast<float2*>(outU)[idx0 + 1] = make_float2(u[di][2 * q2 + 1].x, u[di][2 * q2 + 1].y);
    }
}

extern "C" void kernel_launch(void* const* d_in, const int* in_sizes, int n_in,
                              void* d_out, int out_size, void* d_ws, size_t ws_size,
                              hipStream_t stream) {
  const float* M  = (const float*)d_in[0];
  const float* tv = (const float*)d_in[1];
  const int Nb = in_sizes[0] / (NN * NN);   // 8
  tv_kernel<<<dim3(Nb), dim3(NTHREADS), 0, stream>>>(M, tv, (float*)d_out, Nb);
}